// Round 13
// baseline (282.014 us; speedup 1.0000x reference)
//
#include <hip/hip_runtime.h>
#include <stdint.h>
#include <math.h>

// ---------------- problem constants ----------------
namespace {
constexpr int Bn = 512, Dn = 128, Wn = 30, Kn = 5;
constexpr int HWn = 900;   // 30*30
constexpr int TQ  = 225;   // float4 pixel-quads per image

// workspace float offsets (tiny: only per-query constants)
constexpr size_t OFF_A  = 0;                         // Kn*Dn = 640
constexpr size_t OFF_SA = OFF_A + (size_t)Kn * Dn;   // 5 (pad 8)
constexpr size_t OFF_C0 = OFF_SA + 8;                // 5 (pad 8)

// output float offsets (centroids, attention_maps, stop_logits concatenated)
constexpr size_t OUT_CENT = 0;
constexpr size_t OUT_ATTN = (size_t)Bn * Kn * 2;               // 5120
constexpr size_t OUT_STOP = OUT_ATTN + (size_t)Bn * Kn * HWn;  // 2309120
}  // namespace

struct FoldedKeys { uint32_t k1[5]; uint32_t k2[5]; };

// ---------------- threefry2x32 (JAX partitionable, 20 rounds) ----------------
__host__ __device__ static inline uint32_t rotl32(uint32_t x, int d) {
  return (x << d) | (x >> (32 - d));
}

__host__ __device__ static inline void threefry2x32(uint32_t k1, uint32_t k2,
                                                    uint32_t& x0, uint32_t& x1) {
  uint32_t k3 = k1 ^ k2 ^ 0x1BD11BDAu;
  x0 += k1; x1 += k2;
#define TF_R(rot) { x0 += x1; x1 = rotl32(x1, rot); x1 ^= x0; }
  TF_R(13) TF_R(15) TF_R(26) TF_R(6)   x0 += k2; x1 += k3 + 1u;
  TF_R(17) TF_R(29) TF_R(16) TF_R(24)  x0 += k3; x1 += k1 + 2u;
  TF_R(13) TF_R(15) TF_R(26) TF_R(6)   x0 += k1; x1 += k2 + 3u;
  TF_R(17) TF_R(29) TF_R(16) TF_R(24)  x0 += k2; x1 += k3 + 4u;
  TF_R(13) TF_R(15) TF_R(26) TF_R(6)   x0 += k3; x1 += k1 + 5u;
#undef TF_R
}

// ---------------- reduction helpers ----------------
__device__ static inline float wsum(float v) {
#pragma unroll
  for (int o = 32; o; o >>= 1) v += __shfl_xor(v, o, 64);
  return v;
}
__device__ static inline float bsum2(float v, float* scr) {  // 128-thread block
  v = wsum(v);
  if ((threadIdx.x & 63) == 0) scr[threadIdx.x >> 6] = v;
  __syncthreads();
  float r = scr[0] + scr[1];
  __syncthreads();
  return r;
}

// ---------------- kernel 0: per-query constants ----------------
// q = LN(clue)@wq.T+bq ; qk = q@wk ; A = fn_g*qk ; SA = sum A ; C0 = fn_b.qk + q.bk
__global__ __launch_bounds__(128) void k_prep(
    const float* __restrict__ clue, const float* __restrict__ wq,
    const float* __restrict__ bq, const float* __restrict__ wk,
    const float* __restrict__ bk, const float* __restrict__ qn_g,
    const float* __restrict__ qn_b, const float* __restrict__ fn_g,
    const float* __restrict__ fn_b, float* __restrict__ ws) {
  __shared__ float scr[2];
  __shared__ float lnc[Dn], qrow[Dn], qkrow[Dn];
  const int k = blockIdx.x, t = threadIdx.x;
  float xv = clue[(size_t)k * Dn + t];
  float m = bsum2(xv, scr) * (1.0f / Dn);
  float dd = xv - m;
  float var = bsum2(dd * dd, scr) * (1.0f / Dn);
  float r = 1.0f / sqrtf(var + 1e-5f);
  lnc[t] = dd * r * qn_g[t] + qn_b[t];
  __syncthreads();
  {
    float acc = bq[t];
    const float* wr = wq + (size_t)t * Dn;
    for (int e = 0; e < Dn; ++e) acc += lnc[e] * wr[e];
    qrow[t] = acc;
  }
  __syncthreads();
  {
    float acc = 0.f;
    for (int d = 0; d < Dn; ++d) acc += qrow[d] * wk[(size_t)d * Dn + t];
    qkrow[t] = acc;
    ws[OFF_A + (size_t)k * Dn + t] = fn_g[t] * acc;
  }
  __syncthreads();
  float sa = bsum2(fn_g[t] * qkrow[t], scr);
  float c0 = bsum2(fn_b[t] * qkrow[t] + qrow[t] * bk[t], scr);
  if (t == 0) {
    ws[OFF_SA + k] = sa;
    ws[OFF_C0 + k] = c0;
  }
}

// ---------------- kernel 1: everything per image, fully fused ----------------
// Exactly R5's structure (best measured: 124.9 us, VGPR=128) with ONE change:
// phase B uses the validated fixed-max softmax (noisy<=50 -> p=exp(noisy-50),
// ratios exact) -> ONE 5-value reduction round per k instead of max+Z+4sums.
// __launch_bounds__(256,4) pins VGPR <= 512/4 = 128 (R12 lesson: 132 VGPR
// crossed the occupancy cliff, 22% -> 11.7%, and cost 59 us).
// Phase A: 8-deep float4 batches. Phase C: reverse-channel re-read (L3-hot).
__global__ __launch_bounds__(256, 4) void k_all(
    const float* __restrict__ x, const float* __restrict__ ws,
    const float* __restrict__ wv, const float* __restrict__ bv,
    const float* __restrict__ sw1, const float* __restrict__ sb1,
    const float* __restrict__ sw2, const float* __restrict__ sb2,
    const float* __restrict__ fn_g, const float* __restrict__ fn_b,
    float* __restrict__ out, FoldedKeys keys) {
  __shared__ float Al[Kn * Dn];   // phase A: fn_g*qk ; phase D: reused as af
  __shared__ float wl[Kn * HWn];  // w = attn*rstd
  __shared__ float dots[Kn * Dn];
  __shared__ float att[Kn * Dn];
  __shared__ float hbuf[Kn * 64];
  __shared__ float scrS[4 * 5];   // per-warp partials, 5 sums
  __shared__ float bc[4];         // broadcast 1/Z
  __shared__ float caL[8], entL[8];
  const int b = blockIdx.x, t = threadIdx.x;
  for (int i = t; i < Kn * Dn; i += 256) Al[i] = ws[OFF_A + i];
  __syncthreads();
  const bool act = (t < TQ);
  const float4* xq = (const float4*)(x + (size_t)b * Dn * HWn);

  // ---- phase A: stream this image once (R5's 8-deep float4 batches) ----
  float sm[4] = {0, 0, 0, 0}, sq[4] = {0, 0, 0, 0};
  float sd[5][4] = {};
  {
    const float4* xt = xq + (act ? t : 0);
    for (int e0 = 0; e0 < Dn; e0 += 8) {
      float4 vb[8];
#pragma unroll
      for (int j = 0; j < 8; ++j) vb[j] = xt[(size_t)(e0 + j) * TQ];
#pragma unroll
      for (int j = 0; j < 8; ++j) {
        const int e = e0 + j;
        float a0 = Al[e], a1 = Al[Dn + e], a2 = Al[2 * Dn + e],
              a3 = Al[3 * Dn + e], a4 = Al[4 * Dn + e];
        float vv[4] = {vb[j].x, vb[j].y, vb[j].z, vb[j].w};
#pragma unroll
        for (int c = 0; c < 4; ++c) {
          sm[c] += vv[c];
          sq[c] += vv[c] * vv[c];
          sd[0][c] += vv[c] * a0; sd[1][c] += vv[c] * a1;
          sd[2][c] += vv[c] * a2; sd[3][c] += vv[c] * a3;
          sd[4][c] += vv[c] * a4;
        }
      }
    }
  }
  float r[4], mr[4], base[5][4], cum[4], rw[4], cl[4];
  {
    float SA[5], C0[5];
#pragma unroll
    for (int k = 0; k < 5; ++k) { SA[k] = ws[OFF_SA + k]; C0[k] = ws[OFF_C0 + k]; }
#pragma unroll
    for (int c = 0; c < 4; ++c) {
      float m = sm[c] * (1.0f / Dn);
      float var = sq[c] * (1.0f / Dn) - m * m;
      r[c] = 1.0f / sqrtf(var + 1e-5f);
      mr[c] = m * r[c];
      cum[c] = 1.0f;
      int n = 4 * t + c;
      rw[c] = (float)(n / Wn);
      cl[c] = (float)(n % Wn);
#pragma unroll
      for (int k = 0; k < 5; ++k)
        base[k][c] = (r[c] * (sd[k][c] - m * SA[k]) + C0[k]) *
                     0.08838834764831844f;  // 1/sqrt(128)
    }
  }

  // ---- phase B: 5 gumbel-softmax steps, fixed max = 50, one reduction ----
  for (int k = 0; k < 5; ++k) {
    const uint32_t fk1 = keys.k1[k], fk2 = keys.k2[k];
    float pv[4], P[5] = {0, 0, 0, 0, 0};
#pragma unroll
    for (int c = 0; c < 4; ++c) {
      float noisy;
      if (act) {
        float s = base[k][c] + logf(cum[c]);
        s = fminf(fmaxf(s, -50.f), 50.f);
        uint32_t x0 = 0u, x1 = (uint32_t)(b * HWn + 4 * t + c);  // counter (0,j)
        threefry2x32(fk1, fk2, x0, x1);
        uint32_t bits = x0 ^ x1;
        float u = __uint_as_float((bits >> 9) | 0x3f800000u) - 1.0f;
        u = fmaxf(u, 1e-10f);
        float g = -logf(-logf(u));
        noisy = fminf(fmaxf(s + g, -50.f), 50.f);
      } else {
        noisy = -1e30f;
      }
      float pl = noisy - 50.0f;  // log of unnormalized p
      float p = expf(pl);        // exactly 0 for inactive lanes
      pv[c] = p;
      P[0] += p; P[1] += p * rw[c]; P[2] += p * cl[c];
      P[3] += p * pl; P[4] += p * mr[c];
    }
#pragma unroll
    for (int q = 0; q < 5; ++q) P[q] = wsum(P[q]);
    if ((t & 63) == 0) {
      int w = t >> 6;
#pragma unroll
      for (int q = 0; q < 5; ++q) scrS[w * 5 + q] = P[q];
    }
    __syncthreads();
    if (t == 0) {
      float S0 = 0, S1 = 0, S2 = 0, S3 = 0, S4 = 0;
#pragma unroll
      for (int w = 0; w < 4; ++w) {
        S0 += scrS[w * 5 + 0]; S1 += scrS[w * 5 + 1]; S2 += scrS[w * 5 + 2];
        S3 += scrS[w * 5 + 3]; S4 += scrS[w * 5 + 4];
      }
      const float invZ = 1.0f / S0;
      out[OUT_CENT + ((size_t)(b * Kn + k)) * 2 + 0] = S1 * invZ;
      out[OUT_CENT + ((size_t)(b * Kn + k)) * 2 + 1] = S2 * invZ;
      caL[k] = S4 * invZ;
      // sum a*log a = S3/Z - log Z ; ent = -(that)/log(900)
      entL[k] = -(S3 * invZ - logf(S0)) * 0.14700905142472002f;  // 1/log(900)
      bc[0] = invZ;
    }
    __syncthreads();
    const float invZ = bc[0];
    if (act) {
      float a0 = pv[0] * invZ, a1 = pv[1] * invZ,
            a2 = pv[2] * invZ, a3 = pv[3] * invZ;
      *(float4*)&out[OUT_ATTN + ((size_t)(b * Kn + k)) * HWn + 4 * t] =
          make_float4(a0, a1, a2, a3);
      *(float4*)&wl[(size_t)k * HWn + 4 * t] =
          make_float4(a0 * r[0], a1 * r[1], a2 * r[2], a3 * r[3]);
      cum[0] = fmaxf(cum[0] * (1.0f - 0.9f * a0), 1e-6f);
      cum[1] = fmaxf(cum[1] * (1.0f - 0.9f * a1), 1e-6f);
      cum[2] = fmaxf(cum[2] * (1.0f - 0.9f * a2), 1e-6f);
      cum[3] = fmaxf(cum[3] * (1.0f - 0.9f * a3), 1e-6f);
    }
    __syncthreads();  // protect scrS/bc before next k
  }

  // ---- phase C: attended dots; re-read image in reverse channel order ----
  const int lane = t & 63, wid = t >> 6;
  for (int gi = 0; gi < 4; ++gi) {
    const int g = 15 - (gi * 4 + wid);  // descending channel groups
    const int d0 = g * 8;
    float acc[8][5] = {};
    for (int i0 = 0; i0 < 4; ++i0) {
      const int i = i0 * 64 + lane;
      if (i < TQ) {
        float4 v[8];
#pragma unroll
        for (int j = 0; j < 8; ++j) v[j] = xq[(size_t)(d0 + j) * TQ + i];
        float w4[5][4];
#pragma unroll
        for (int k = 0; k < 5; ++k) {
          float4 wv4 = *(const float4*)&wl[k * HWn + 4 * i];
          w4[k][0] = wv4.x; w4[k][1] = wv4.y; w4[k][2] = wv4.z; w4[k][3] = wv4.w;
        }
#pragma unroll
        for (int j = 0; j < 8; ++j)
#pragma unroll
          for (int k = 0; k < 5; ++k)
            acc[j][k] += v[j].x * w4[k][0] + v[j].y * w4[k][1] +
                         v[j].z * w4[k][2] + v[j].w * w4[k][3];
      }
    }
#pragma unroll
    for (int j = 0; j < 8; ++j)
#pragma unroll
      for (int k = 0; k < 5; ++k) {
        float s = wsum(acc[j][k]);
        if (lane == 0) dots[k * Dn + d0 + j] = s;
      }
  }
  __syncthreads();

  // ---- phase D: LN-combine + wv proj + MLP + stop ----
  float* af = Al;  // reuse (phase-A use of Al is long done)
  for (int i = t; i < Kn * Dn; i += 256) {
    int k = i >> 7, e = i & 127;
    af[i] = fn_g[e] * (dots[i] - caL[k]) + fn_b[e];
  }
  __syncthreads();
  for (int i = t; i < Kn * Dn; i += 256) {
    int k = i >> 7, d2 = i & 127;
    const float4* wr = (const float4*)(wv + (size_t)d2 * Dn);
    const float4* afq = (const float4*)&af[k << 7];
    float s = bv[d2];
    for (int e = 0; e < Dn / 4; ++e) {
      float4 a = afq[e], w = wr[e];
      s += a.x * w.x + a.y * w.y + a.z * w.z + a.w * w.w;
    }
    att[i] = s;
  }
  __syncthreads();
  for (int i = t; i < Kn * 64; i += 256) {
    int k = i >> 6, j = i & 63;
    const float* sr = sw1 + (size_t)j * (Dn + 1);
    float s = sb1[j];
    for (int e = 0; e < Dn; ++e) s += sr[e] * att[(k << 7) + e];
    s += entL[k] * sr[Dn];
    // exact GELU: x * (erf(x/sqrt(2)) + 1) / 2
    hbuf[i] = s * (erff(s * 0.7071067811865475f) + 1.0f) * 0.5f;
  }
  __syncthreads();
  if (t < Kn) {
    float s = sb2[0];
    for (int j = 0; j < 64; ++j) s += hbuf[(t << 6) + j] * sw2[j];
    out[OUT_STOP + (size_t)b * Kn + t] = s;
  }
}

// ---------------- launch ----------------
extern "C" void kernel_launch(void* const* d_in, const int* in_sizes, int n_in,
                              void* d_out, int out_size, void* d_ws, size_t ws_size,
                              hipStream_t stream) {
  (void)in_sizes; (void)n_in; (void)out_size; (void)ws_size;
  const float* features = (const float*)d_in[0];
  const float* clue     = (const float*)d_in[1];
  const float* wq       = (const float*)d_in[2];
  const float* bq       = (const float*)d_in[3];
  const float* wk       = (const float*)d_in[4];
  const float* bk       = (const float*)d_in[5];
  const float* wv       = (const float*)d_in[6];
  const float* bv       = (const float*)d_in[7];
  const float* sw1      = (const float*)d_in[8];
  const float* sb1      = (const float*)d_in[9];
  const float* sw2      = (const float*)d_in[10];
  const float* sb2      = (const float*)d_in[11];
  const float* qn_g     = (const float*)d_in[12];
  const float* qn_b     = (const float*)d_in[13];
  const float* fn_g     = (const float*)d_in[14];
  const float* fn_b     = (const float*)d_in[15];
  float* ws  = (float*)d_ws;
  float* out = (float*)d_out;

  // fold_in(key(42), k) on host: full threefry of (0,k) with key (0,42).
  FoldedKeys fk;
  for (int k = 0; k < Kn; ++k) {
    uint32_t x0 = 0u, x1 = (uint32_t)k;
    threefry2x32(0u, 42u, x0, x1);
    fk.k1[k] = x0; fk.k2[k] = x1;
  }

  hipLaunchKernelGGL(k_prep, dim3(Kn), dim3(128), 0, stream,
                     clue, wq, bq, wk, bk, qn_g, qn_b, fn_g, fn_b, ws);
  hipLaunchKernelGGL(k_all, dim3(Bn), dim3(256), 0, stream,
                     features, ws, wv, bv, sw1, sb1, sw2, sb2, fn_g, fn_b,
                     out, fk);
}